// Round 5
// baseline (11516.760 us; speedup 1.0000x reference)
//
#include <hip/hip_runtime.h>
#include <hip/hip_bf16.h>

typedef __attribute__((ext_vector_type(8))) short bf16x8;
typedef __attribute__((ext_vector_type(4))) float f32x4;
typedef __attribute__((ext_vector_type(2))) unsigned uint32x2;

#define NBLK 256
#define NTHR 512

__device__ __forceinline__ unsigned short f2bf(float f) {
  unsigned int u = __float_as_uint(f);
  unsigned int r = (u + 0x7FFFu + ((u >> 16) & 1u)) >> 16;
  return (unsigned short)r;
}

// h loads: normal cached (L1/L2) — correctness via per-step acquire fence
__device__ __forceinline__ bf16x8 ldg_b128(const unsigned short* p) {
  bf16x8 r;
  asm volatile("global_load_dwordx4 %0, %1, off"
               : "=v"(r) : "v"(p) : "memory");
  return r;
}
// h stores: write-through to the coherence point (no dirty L2 lines)
__device__ __forceinline__ void stg_b16_coh(unsigned short* p, unsigned v) {
  asm volatile("global_store_short %0, %1, off sc0 sc1"
               :: "v"(p), "v"(v) : "memory");
}

// Pack weights bf16: Wp[jb 128][c 32][k 2048], c = jj*4 + g.
__global__ __launch_bounds__(256) void pack_w(const float* __restrict__ Wx,
                                              const float* __restrict__ Wh,
                                              unsigned short* __restrict__ Wp) {
  int idx = blockIdx.x * 256 + threadIdx.x;
  int k  = idx & 2047;
  int c  = (idx >> 11) & 31;
  int jb = idx >> 16;
  int g  = c & 3;
  int j  = jb * 8 + (c >> 2);
  float v = (k < 1024) ? Wh[((size_t)(g * 1024 + k)) * 1024 + j]
                       : Wx[((size_t)(g * 1024 + (k - 1024))) * 1024 + j];
  Wp[idx] = f2bf(v);
}

// Pack x to bf16 in per-wave A-fragment order:
// flat = (((t*2+rb)*2+wn)*16+s)*2048 + (wr*64+lane)*8 + e
__global__ __launch_bounds__(256) void pack_x(const float* __restrict__ x,
                                              unsigned short* __restrict__ xpk) {
  size_t idx = (size_t)blockIdx.x * 256 + threadIdx.x;   // 8,388,608 chunks of 8
  int lane = (int)(idx & 63);
  int wr   = (int)((idx >> 6) & 3);
  int s    = (int)((idx >> 8) & 15);
  int wn   = (int)((idx >> 12) & 1);
  int rb   = (int)((idx >> 13) & 1);
  int t    = (int)(idx >> 14);
  int a15 = lane & 15, hi = lane >> 4;
  int row = rb * 64 + wr * 16 + a15;
  int k   = (2 * s + wn) * 32 + hi * 8;
  const float* src = x + ((size_t)row * 512 + t) * 1024 + k;
  float4 f0 = *(const float4*)src;
  float4 f1 = *(const float4*)(src + 4);
  float fl[8] = {f0.x, f0.y, f0.z, f0.w, f1.x, f1.y, f1.z, f1.w};
  union { bf16x8 v; unsigned short us[8]; } u;
  #pragma unroll
  for (int e = 0; e < 8; ++e) u.us[e] = f2bf(fl[e]);
  *(bf16x8*)(xpk + idx * 8) = u.v;
}

__global__ __launch_bounds__(512, 2) void lstm_persist(
    const float* __restrict__ x,
    const unsigned short* __restrict__ xpk,   // may be null -> f32 fallback
    const unsigned short* __restrict__ Wp,
    const float* __restrict__ bias,
    unsigned short* __restrict__ h0,
    unsigned short* __restrict__ h1,
    float* __restrict__ out,
    unsigned* __restrict__ bar)   // bar[rb*128 + jb] = step flags
{
  __shared__ unsigned short Wlds[32][2052];   // 131,328 B
  __shared__ float gt[2][64][33];             // 16,896 B

  const int tid = threadIdx.x;
  const int bx  = blockIdx.x;
  const int xcd = bx & 7;
  const int rb  = xcd >> 2;
  const int jb  = (bx >> 3) * 4 + (xcd & 3);   // 0..127, bijective with rb
  const int row0 = rb * 64;

  // weight slice -> LDS (once)
  #pragma unroll
  for (int rep = 0; rep < 16; ++rep) {
    int ch = rep * 512 + tid;
    int c  = ch >> 8;
    int k8 = (ch & 255) * 8;
    *(bf16x8*)&Wlds[c][k8] = *(const bf16x8*)(Wp + ((size_t)(jb * 32 + c)) * 2048 + k8);
  }

  const int lane = tid & 63;
  const int w    = tid >> 6;
  const int wr   = w >> 1;
  const int wn   = w & 1;
  const int a15  = lane & 15;
  const int hi   = lane >> 4;

  const int um  = tid >> 3;
  const int uj  = tid & 7;
  const int ujg = jb * 8 + uj;
  const float bi = bias[ujg], bf_ = bias[1024 + ujg];
  const float bo = bias[2048 + ujg], bu = bias[3072 + ujg];
  float creg = 0.f;

  const int rowg = row0 + wr * 16 + a15;
  const float* xrow = x + (size_t)rowg * 512 * 1024;
  const size_t xpk_lane = ((size_t)wr * 64 + lane) * 8;
  const unsigned* fpoll = bar + rb * 128 + (lane << 1);   // dwordx2 per lane covers 128 flags

  __syncthreads();

  unsigned short* hb[2] = {h0, h1};
  bf16x8 xreg[16];

  // prologue: x fragments for t=0, fully drained
  if (xpk) {
    const unsigned short* xs = xpk + (((size_t)0 * 2 + rb) * 2 + wn) * 16 * 2048 + xpk_lane;
    #pragma unroll
    for (int s = 0; s < 16; ++s)
      asm volatile("global_load_dwordx4 %0, %1, off" : "=v"(xreg[s]) : "v"(xs + s * 2048) : "memory");
    asm volatile("s_waitcnt vmcnt(0)" ::: "memory");
    __builtin_amdgcn_sched_barrier(0);
  } else {
    const float* xt = xrow + hi * 8;
    #pragma unroll
    for (int s = 0; s < 16; ++s) {
      const float* xp = xt + (2 * s + wn) * 32;
      float4 f0 = *(const float4*)xp;
      float4 f1 = *(const float4*)(xp + 4);
      float fl[8] = {f0.x, f0.y, f0.z, f0.w, f1.x, f1.y, f1.z, f1.w};
      union { bf16x8 v; unsigned short us[8]; } u;
      #pragma unroll
      for (int e = 0; e < 8; ++e) u.us[e] = f2bf(fl[e]);
      xreg[s] = u.v;
    }
  }

  for (int t = 0; t < 512; ++t) {
    const unsigned short* hc = hb[t & 1];
    unsigned short* hn = hb[(t + 1) & 1];

    // phase 1: issue all 16 h loads (cached; L2 shares the panel across the
    // XCD's blocks). Stale lines were invalidated by the acquire fence at the
    // end of the previous iteration (t=0: kernel-launch acquire covers).
    bf16x8 hreg[16];
    const unsigned short* hbase = hc + (size_t)rowg * 1024 + hi * 8;
    #pragma unroll
    for (int s = 0; s < 16; ++s)
      hreg[s] = ldg_b128(hbase + (2 * s + wn) * 32);
    __builtin_amdgcn_sched_barrier(0);

    // phase 2: x MFMAs (xreg already resident; h loads in flight under them)
    f32x4 acc0 = {}, acc1 = {};
    #pragma unroll
    for (int s = 0; s < 16; ++s) {
      const int kk = 1024 + (2 * s + wn) * 32 + hi * 8;
      bf16x8 b0 = *(const bf16x8*)&Wlds[a15][kk];
      bf16x8 b1 = *(const bf16x8*)&Wlds[16 + a15][kk];
      acc0 = __builtin_amdgcn_mfma_f32_16x16x32_bf16(xreg[s], b0, acc0, 0, 0, 0);
      acc1 = __builtin_amdgcn_mfma_f32_16x16x32_bf16(xreg[s], b1, acc1, 0, 0, 0);
    }

    // phase 3: h MFMAs with split counted waits (oldest 8 first)
    asm volatile("s_waitcnt vmcnt(8)" ::: "memory");
    __builtin_amdgcn_sched_barrier(0);
    #pragma unroll
    for (int s = 0; s < 8; ++s) {
      const int kk = (2 * s + wn) * 32 + hi * 8;
      bf16x8 b0 = *(const bf16x8*)&Wlds[a15][kk];
      bf16x8 b1 = *(const bf16x8*)&Wlds[16 + a15][kk];
      acc0 = __builtin_amdgcn_mfma_f32_16x16x32_bf16(hreg[s], b0, acc0, 0, 0, 0);
      acc1 = __builtin_amdgcn_mfma_f32_16x16x32_bf16(hreg[s], b1, acc1, 0, 0, 0);
    }
    asm volatile("s_waitcnt vmcnt(0)" ::: "memory");
    __builtin_amdgcn_sched_barrier(0);
    #pragma unroll
    for (int s = 8; s < 16; ++s) {
      const int kk = (2 * s + wn) * 32 + hi * 8;
      bf16x8 b0 = *(const bf16x8*)&Wlds[a15][kk];
      bf16x8 b1 = *(const bf16x8*)&Wlds[16 + a15][kk];
      acc0 = __builtin_amdgcn_mfma_f32_16x16x32_bf16(hreg[s], b0, acc0, 0, 0, 0);
      acc1 = __builtin_amdgcn_mfma_f32_16x16x32_bf16(hreg[s], b1, acc1, 0, 0, 0);
    }

    // phase 4: gate exchange through LDS
    #pragma unroll
    for (int r = 0; r < 4; ++r) {
      gt[wn][wr * 16 + hi * 4 + r][a15]      = acc0[r];
      gt[wn][wr * 16 + hi * 4 + r][16 + a15] = acc1[r];
    }
    __syncthreads();

    // phase 5: elementwise LSTM update + write-through h store
    float vi = gt[0][um][uj * 4 + 0] + gt[1][um][uj * 4 + 0] + bi;
    float vf = gt[0][um][uj * 4 + 1] + gt[1][um][uj * 4 + 1] + bf_;
    float vo = gt[0][um][uj * 4 + 2] + gt[1][um][uj * 4 + 2] + bo;
    float vu = gt[0][um][uj * 4 + 3] + gt[1][um][uj * 4 + 3] + bu;
    float iv = 1.f / (1.f + expf(-vi));
    float fv = 1.f / (1.f + expf(-vf));
    float ov = 1.f / (1.f + expf(-vo));
    float uv = tanhf(vu);
    creg = fv * creg + iv * uv;
    float hv = ov * tanhf(creg);
    stg_b16_coh(hn + (size_t)(row0 + um) * 1024 + ujg, (unsigned)f2bf(hv));
    if (t == 511) {
      out[(size_t)(row0 + um) * 1024 + ujg] = hv;
      break;
    }

    // phase 6: drain h store, block-local barrier, publish arrival flag
    asm volatile("s_waitcnt vmcnt(0)" ::: "memory");
    __builtin_amdgcn_s_barrier();
    if (tid == 0) {
      const unsigned* p = bar + rb * 128 + jb;
      unsigned val = (unsigned)(t + 1);
      asm volatile("global_store_dword %0, %1, off sc0 sc1"
                   :: "v"(p), "v"(val) : "memory");
    }

    // phase 7: issue x[t+1] prefetch (latency hides under the poll)
    if (xpk) {
      const unsigned short* xs = xpk + (((size_t)(t + 1) * 2 + rb) * 2 + wn) * 16 * 2048 + xpk_lane;
      #pragma unroll
      for (int s = 0; s < 16; ++s)
        asm volatile("global_load_dwordx4 %0, %1, off" : "=v"(xreg[s]) : "v"(xs + s * 2048) : "memory");
    } else {
      const float* xt = xrow + (size_t)(t + 1) * 1024 + hi * 8;
      #pragma unroll
      for (int s = 0; s < 16; ++s) {
        const float* xp = xt + (2 * s + wn) * 32;
        float4 f0 = *(const float4*)xp;
        float4 f1 = *(const float4*)(xp + 4);
        float fl[8] = {f0.x, f0.y, f0.z, f0.w, f1.x, f1.y, f1.z, f1.w};
        union { bf16x8 v; unsigned short us[8]; } u;
        #pragma unroll
        for (int e = 0; e < 8; ++e) u.us[e] = f2bf(fl[e]);
        xreg[s] = u.v;
      }
    }

    // phase 8: every wave polls its group's 128 flags (one dwordx2 per lane).
    // The vmcnt(0) inside the poll also drains the x prefetch.
    for (;;) {
      uint32x2 v;
      asm volatile("global_load_dwordx2 %0, %1, off sc0 sc1"
                   : "=v"(v) : "v"(fpoll) : "memory");
      asm volatile("s_waitcnt vmcnt(0)" ::: "memory");
      if (__all(v.x > (unsigned)t && v.y > (unsigned)t)) break;
      __builtin_amdgcn_s_sleep(1);
    }
    // acquire: invalidate (clean) L1/L2 lines so next-step h loads see the
    // write-through values from other XCDs. xreg is in registers — unaffected.
    __builtin_amdgcn_fence(__ATOMIC_ACQUIRE, "agent");
    __builtin_amdgcn_sched_barrier(0);
  }
}

extern "C" void kernel_launch(void* const* d_in, const int* in_sizes, int n_in,
                              void* d_out, int out_size, void* d_ws, size_t ws_size,
                              hipStream_t stream) {
  const float* x    = (const float*)d_in[0];
  // d_in[1] = adjacency (unused)
  const float* Wx   = (const float*)d_in[2];
  const float* Wh   = (const float*)d_in[3];
  const float* bias = (const float*)d_in[4];
  float* out = (float*)d_out;

  // ws: Wp 16MB | h0 | h1 | bar (4KB) | (xpk @ 32MB, 134MB)
  char* ws = (char*)d_ws;
  unsigned short* Wp = (unsigned short*)ws;
  unsigned short* h0 = (unsigned short*)(ws + 16777216);
  unsigned short* h1 = h0 + 128 * 1024;
  unsigned* bar = (unsigned*)(ws + 16777216 + 2 * 262144);
  const size_t XPK_OFF = 33554432;
  const size_t XPK_SZ  = 134217728;
  unsigned short* xpk = (ws_size >= XPK_OFF + XPK_SZ)
                        ? (unsigned short*)(ws + XPK_OFF) : nullptr;

  pack_w<<<32768, 256, 0, stream>>>(Wx, Wh, Wp);
  if (xpk) pack_x<<<32768, 256, 0, stream>>>(x, xpk);
  hipMemsetAsync(h0, 0, 128 * 1024 * sizeof(unsigned short), stream);
  hipMemsetAsync(bar, 0, 4096, stream);

  (void)in_sizes; (void)n_in;
  lstm_persist<<<NBLK, NTHR, 0, stream>>>(x, xpk, Wp, bias, h0, h1, out, bar);
}

// Round 7
// 4208.308 us; speedup vs baseline: 2.7367x; 2.7367x over previous
//
#include <hip/hip_runtime.h>
#include <hip/hip_bf16.h>

typedef __attribute__((ext_vector_type(8))) short bf16x8;
typedef __attribute__((ext_vector_type(4))) float f32x4;
typedef __attribute__((ext_vector_type(2))) unsigned uint32x2;

#define NBLK 256
#define NTHR 512

__device__ __forceinline__ unsigned short f2bf(float f) {
  unsigned int u = __float_as_uint(f);
  unsigned int r = (u + 0x7FFFu + ((u >> 16) & 1u)) >> 16;
  return (unsigned short)r;
}

// coherence-point (bypass L1/L2) ops for the h exchange
__device__ __forceinline__ bf16x8 ldg_b128_coh(const unsigned short* p) {
  bf16x8 r;
  asm volatile("global_load_dwordx4 %0, %1, off sc0 sc1"
               : "=v"(r) : "v"(p) : "memory");
  return r;
}
__device__ __forceinline__ void stg_b16_coh(unsigned short* p, unsigned v) {
  asm volatile("global_store_short %0, %1, off sc0 sc1"
               :: "v"(p), "v"(v) : "memory");
}

// Pack weights bf16: Wp[jb 128][c 32][k 2048], c = jj*4 + g.
__global__ __launch_bounds__(256) void pack_w(const float* __restrict__ Wx,
                                              const float* __restrict__ Wh,
                                              unsigned short* __restrict__ Wp) {
  int idx = blockIdx.x * 256 + threadIdx.x;
  int k  = idx & 2047;
  int c  = (idx >> 11) & 31;
  int jb = idx >> 16;
  int g  = c & 3;
  int j  = jb * 8 + (c >> 2);
  float v = (k < 1024) ? Wh[((size_t)(g * 1024 + k)) * 1024 + j]
                       : Wx[((size_t)(g * 1024 + (k - 1024))) * 1024 + j];
  Wp[idx] = f2bf(v);
}

// Pack x to bf16 in per-wave A-fragment order:
// flat = (((t*2+rb)*2+wn)*16+s)*2048 + (wr*64+lane)*8 + e
__global__ __launch_bounds__(256) void pack_x(const float* __restrict__ x,
                                              unsigned short* __restrict__ xpk) {
  size_t idx = (size_t)blockIdx.x * 256 + threadIdx.x;
  int lane = (int)(idx & 63);
  int wr   = (int)((idx >> 6) & 3);
  int s    = (int)((idx >> 8) & 15);
  int wn   = (int)((idx >> 12) & 1);
  int rb   = (int)((idx >> 13) & 1);
  int t    = (int)(idx >> 14);
  int a15 = lane & 15, hi = lane >> 4;
  int row = rb * 64 + wr * 16 + a15;
  int k   = (2 * s + wn) * 32 + hi * 8;
  const float* src = x + ((size_t)row * 512 + t) * 1024 + k;
  float4 f0 = *(const float4*)src;
  float4 f1 = *(const float4*)(src + 4);
  float fl[8] = {f0.x, f0.y, f0.z, f0.w, f1.x, f1.y, f1.z, f1.w};
  union { bf16x8 v; unsigned short us[8]; } u;
  #pragma unroll
  for (int e = 0; e < 8; ++e) u.us[e] = f2bf(fl[e]);
  *(bf16x8*)(xpk + idx * 8) = u.v;
}

// Persistent LSTM with per-wave fine-grained flags and incremental h loads.
// bar[(rb*8 + w)*128 + jb] = step value published by wave w of block (rb,jb)
// after ITS 8 rows of h are drained to the coherence point.
__global__ __launch_bounds__(512, 2) void lstm_persist(
    const float* __restrict__ x,
    const unsigned short* __restrict__ xpk,   // may be null -> f32 fallback
    const unsigned short* __restrict__ Wp,
    const float* __restrict__ bias,
    unsigned short* __restrict__ h0,
    unsigned short* __restrict__ h1,
    float* __restrict__ out,
    unsigned* __restrict__ bar)
{
  __shared__ unsigned short Wlds[32][2052];   // 131,328 B
  __shared__ float gt[2][64][33];             // 16,896 B

  const int tid = threadIdx.x;
  const int bx  = blockIdx.x;
  const int xcd = bx & 7;
  const int rb  = xcd >> 2;
  const int jb  = (bx >> 3) * 4 + (xcd & 3);   // 0..127
  const int row0 = rb * 64;

  // weight slice -> LDS (once)
  #pragma unroll
  for (int rep = 0; rep < 16; ++rep) {
    int ch = rep * 512 + tid;
    int c  = ch >> 8;
    int k8 = (ch & 255) * 8;
    *(bf16x8*)&Wlds[c][k8] = *(const bf16x8*)(Wp + ((size_t)(jb * 32 + c)) * 2048 + k8);
  }

  const int lane = tid & 63;
  const int w    = tid >> 6;     // 0..7
  const int wr   = w >> 1;       // row tile (16 rows)
  const int wn   = w & 1;        // K parity
  const int a15  = lane & 15;
  const int hi   = lane >> 4;

  const int um  = tid >> 3;      // elementwise row 0..63 (wave w owns rows 8w..8w+7)
  const int uj  = tid & 7;
  const int ujg = jb * 8 + uj;
  const float bi = bias[ujg], bf_ = bias[1024 + ujg];
  const float bo = bias[2048 + ujg], bu = bias[3072 + ujg];
  float creg = 0.f;

  const int rowg = row0 + wr * 16 + a15;
  const float* xrow = x + (size_t)rowg * 512 * 1024;
  const size_t xpk_lane = ((size_t)wr * 64 + lane) * 8;

  // consumer flag pointers: rows 16wr..16wr+16 <-> producer waves 2wr, 2wr+1.
  // lane L covers producer blocks jb' = 2L, 2L+1 (dwordx2).
  const unsigned* fp0 = bar + (rb * 8 + 2 * wr    ) * 128 + 2 * lane;
  const unsigned* fp1 = bar + (rb * 8 + 2 * wr + 1) * 128 + 2 * lane;
  unsigned* fprod = bar + (rb * 8 + w) * 128 + jb;

  __syncthreads();

  unsigned short* hb[2] = {h0, h1};
  bf16x8 xreg[16];
  f32x4 acc0 = {}, acc1 = {};

  auto xload = [&](int tt) {
    if (xpk) {
      const unsigned short* xs = xpk + ((((size_t)tt * 2 + rb) * 2 + wn) * 16) * 2048 + xpk_lane;
      #pragma unroll
      for (int s = 0; s < 16; ++s)
        asm volatile("global_load_dwordx4 %0, %1, off"
                     : "=v"(xreg[s]) : "v"(xs + s * 2048) : "memory");
    } else {
      const float* xt = xrow + (size_t)tt * 1024 + hi * 8;
      #pragma unroll
      for (int s = 0; s < 16; ++s) {
        const float* xp = xt + (2 * s + wn) * 32;
        float4 f0 = *(const float4*)xp;
        float4 f1 = *(const float4*)(xp + 4);
        float fl[8] = {f0.x, f0.y, f0.z, f0.w, f1.x, f1.y, f1.z, f1.w};
        union { bf16x8 v; unsigned short us[8]; } u;
        #pragma unroll
        for (int e = 0; e < 8; ++e) u.us[e] = f2bf(fl[e]);
        xreg[s] = u.v;
      }
    }
  };

  // prologue: acc = x-part(t=0); then prefetch x(1)
  xload(0);
  asm volatile("s_waitcnt vmcnt(0)" ::: "memory");
  __builtin_amdgcn_sched_barrier(0);
  #pragma unroll
  for (int s = 0; s < 16; ++s) {
    const int kk = 1024 + (2 * s + wn) * 32 + hi * 8;
    bf16x8 b0 = *(const bf16x8*)&Wlds[a15][kk];
    bf16x8 b1 = *(const bf16x8*)&Wlds[16 + a15][kk];
    acc0 = __builtin_amdgcn_mfma_f32_16x16x32_bf16(xreg[s], b0, acc0, 0, 0, 0);
    acc1 = __builtin_amdgcn_mfma_f32_16x16x32_bf16(xreg[s], b1, acc1, 0, 0, 0);
  }
  xload(1);

  for (int t = 0; t < 512; ++t) {
    const unsigned short* hc = hb[t & 1];
    unsigned short* hn = hb[(t + 1) & 1];

    // ---- h-part(t): flag-gated incremental loads, then fixed-order MFMAs.
    // t=0: h is zero -> skip entirely.
    if (t > 0) {
      bf16x8 hreg[16];
      const unsigned short* hbase = hc + (size_t)rowg * 1024 + hi * 8;
      unsigned remaining = 0xFFFFu;
      while (remaining) {
        uint32x2 v0, v1;
        asm volatile("global_load_dwordx2 %0, %1, off sc0 sc1"
                     : "=v"(v0) : "v"(fp0) : "memory");
        asm volatile("global_load_dwordx2 %0, %1, off sc0 sc1"
                     : "=v"(v1) : "v"(fp1) : "memory");
        asm volatile("s_waitcnt vmcnt(0)" ::: "memory");
        __builtin_amdgcn_sched_barrier(0);
        int okA = (v0.x >= (unsigned)t) & (v1.x >= (unsigned)t);
        int okB = (v0.y >= (unsigned)t) & (v1.y >= (unsigned)t);
        unsigned long long be = __ballot(okA);
        unsigned long long bo = __ballot(okB);
        unsigned ready = 0;
        #pragma unroll
        for (int s = 0; s < 16; ++s) {
          const int sh = (2 * s + wn) * 2;   // = jb'-group base / 2
          unsigned g4 = ((unsigned)(be >> sh) & 3u) | ((((unsigned)(bo >> sh)) & 3u) << 2);
          ready |= (g4 == 15u) ? (1u << s) : 0u;
        }
        unsigned newm = ready & remaining;
        if (newm) {
          #pragma unroll
          for (int s = 0; s < 16; ++s)
            if (newm & (1u << s))
              hreg[s] = ldg_b128_coh(hbase + (2 * s + wn) * 32);
          remaining &= ~newm;
        } else {
          __builtin_amdgcn_s_sleep(1);
        }
      }
      asm volatile("s_waitcnt vmcnt(0)" ::: "memory");
      __builtin_amdgcn_sched_barrier(0);
      #pragma unroll
      for (int s = 0; s < 16; ++s) {
        const int kk = (2 * s + wn) * 32 + hi * 8;
        bf16x8 b0 = *(const bf16x8*)&Wlds[a15][kk];
        bf16x8 b1 = *(const bf16x8*)&Wlds[16 + a15][kk];
        acc0 = __builtin_amdgcn_mfma_f32_16x16x32_bf16(hreg[s], b0, acc0, 0, 0, 0);
        acc1 = __builtin_amdgcn_mfma_f32_16x16x32_bf16(hreg[s], b1, acc1, 0, 0, 0);
      }
    }

    // ---- gate exchange through LDS
    #pragma unroll
    for (int r = 0; r < 4; ++r) {
      gt[wn][wr * 16 + hi * 4 + r][a15]      = acc0[r];
      gt[wn][wr * 16 + hi * 4 + r][16 + a15] = acc1[r];
    }
    __syncthreads();

    // ---- elementwise LSTM update; wave-local drain + per-wave flag publish
    float vi = gt[0][um][uj * 4 + 0] + gt[1][um][uj * 4 + 0] + bi;
    float vf = gt[0][um][uj * 4 + 1] + gt[1][um][uj * 4 + 1] + bf_;
    float vo = gt[0][um][uj * 4 + 2] + gt[1][um][uj * 4 + 2] + bo;
    float vu = gt[0][um][uj * 4 + 3] + gt[1][um][uj * 4 + 3] + bu;
    float iv = 1.f / (1.f + expf(-vi));
    float fv = 1.f / (1.f + expf(-vf));
    float ov = 1.f / (1.f + expf(-vo));
    float uv = tanhf(vu);
    creg = fv * creg + iv * uv;
    float hv = ov * tanhf(creg);
    if (t == 511) {
      out[(size_t)(row0 + um) * 1024 + ujg] = hv;
    } else {
      stg_b16_coh(hn + (size_t)(row0 + um) * 1024 + ujg, (unsigned)f2bf(hv));
      asm volatile("s_waitcnt vmcnt(0)" ::: "memory");   // drain THIS wave's 8 rows
      if (lane == 0) {
        unsigned val = (unsigned)(t + 1);
        asm volatile("global_store_dword %0, %1, off sc0 sc1"
                     :: "v"(fprod), "v"(val) : "memory");
      }
    }
    __syncthreads();   // protect gt before next step's writes
    if (t == 511) break;

    // ---- x-part(t+1) into fresh acc (xreg(t+1) drained by vmcnt(0) above)
    __builtin_amdgcn_sched_barrier(0);
    f32x4 nacc0 = {}, nacc1 = {};
    #pragma unroll
    for (int s = 0; s < 16; ++s) {
      const int kk = 1024 + (2 * s + wn) * 32 + hi * 8;
      bf16x8 b0 = *(const bf16x8*)&Wlds[a15][kk];
      bf16x8 b1 = *(const bf16x8*)&Wlds[16 + a15][kk];
      nacc0 = __builtin_amdgcn_mfma_f32_16x16x32_bf16(xreg[s], b0, nacc0, 0, 0, 0);
      nacc1 = __builtin_amdgcn_mfma_f32_16x16x32_bf16(xreg[s], b1, nacc1, 0, 0, 0);
    }
    acc0 = nacc0; acc1 = nacc1;

    // ---- prefetch x(t+2); stays in flight across the next poll
    if (t + 2 < 512) xload(t + 2);
  }
}

extern "C" void kernel_launch(void* const* d_in, const int* in_sizes, int n_in,
                              void* d_out, int out_size, void* d_ws, size_t ws_size,
                              hipStream_t stream) {
  const float* x    = (const float*)d_in[0];
  // d_in[1] = adjacency (unused)
  const float* Wx   = (const float*)d_in[2];
  const float* Wh   = (const float*)d_in[3];
  const float* bias = (const float*)d_in[4];
  float* out = (float*)d_out;

  // ws: Wp 16MB | h0 | h1 | bar (8KB) | (xpk @ 32MB, 134MB)
  char* ws = (char*)d_ws;
  unsigned short* Wp = (unsigned short*)ws;
  unsigned short* h0 = (unsigned short*)(ws + 16777216);
  unsigned short* h1 = h0 + 128 * 1024;
  unsigned* bar = (unsigned*)(ws + 16777216 + 2 * 262144);
  const size_t XPK_OFF = 33554432;
  const size_t XPK_SZ  = 134217728;
  unsigned short* xpk = (ws_size >= XPK_OFF + XPK_SZ)
                        ? (unsigned short*)(ws + XPK_OFF) : nullptr;

  pack_w<<<32768, 256, 0, stream>>>(Wx, Wh, Wp);
  if (xpk) pack_x<<<32768, 256, 0, stream>>>(x, xpk);
  hipMemsetAsync(bar, 0, 8192, stream);

  (void)in_sizes; (void)n_in;
  lstm_persist<<<NBLK, NTHR, 0, stream>>>(x, xpk, Wp, bias, h0, h1, out, bar);
}